// Round 1
// baseline (3102.517 us; speedup 1.0000x reference)
//
#include <hip/hip_runtime.h>
#include <hip/hip_bf16.h>
#include <cstddef>

// ---------------------------------------------------------------- constants
#define B_      4
#define S_      4096
#define D_      1024
#define NH_     8
#define HD_     64
#define STATE_  512           // NH_*HD_
#define PROJ_   2048          // 4*STATE_
#define ROWS_   16384         // B_*S_

typedef float f32x4 __attribute__((ext_vector_type(4)));
typedef __bf16 bf16x8 __attribute__((ext_vector_type(8)));

// ---------------------------------------------------------------- helpers
__device__ __forceinline__ unsigned short bfbits(float f) {
    __hip_bfloat16 h = __float2bfloat16(f);
    return __builtin_bit_cast(unsigned short, h);
}

__device__ __forceinline__ float fast_sigmoid(float x) {
    return __builtin_amdgcn_rcpf(1.0f + __expf(-x));
}

__device__ __forceinline__ float fast_tanh(float x) {
    // 1 - 2/(exp(2x)+1); saturates correctly at +/-inf
    return 1.0f - 2.0f * __builtin_amdgcn_rcpf(__expf(2.0f * x) + 1.0f);
}

__device__ __forceinline__ void async_copy16(void* lds, const void* g) {
    __builtin_amdgcn_global_load_lds(
        (const __attribute__((address_space(1))) unsigned int*)g,
        (__attribute__((address_space(3))) unsigned int*)lds,
        16, 0, 0);
}

// ---------------------------------------------------------------- fp32 -> bf16 convert
__global__ __launch_bounds__(256) void f2bf(const float* __restrict__ in,
                                            unsigned short* __restrict__ out, int n4) {
    int i = blockIdx.x * 256 + threadIdx.x;
    if (i < n4) {
        float4 v = ((const float4*)in)[i];
        ushort4 o;
        o.x = bfbits(v.x); o.y = bfbits(v.y); o.z = bfbits(v.z); o.w = bfbits(v.w);
        ((ushort4*)out)[i] = o;
    }
}

// ---------------------------------------------------------------- GEMM  C[M,N] = A[M,K] * B[N,K]^T
// m97-style: 128x128 tile, BK=32, 256 threads (2x2 waves of 64x64),
// global_load_lds width-16 staging, 16x16x32 bf16 MFMA.
__device__ __forceinline__ void store_out(float* p, float v) { *p = v; }
__device__ __forceinline__ void store_out(__hip_bfloat16* p, float v) { *p = __float2bfloat16(v); }

template <typename OutT>
__global__ __launch_bounds__(256, 1) void gemm_bt(const unsigned short* __restrict__ A,
                                                  const unsigned short* __restrict__ Bm,
                                                  OutT* __restrict__ C,
                                                  int M, int N, int K) {
    __shared__ __align__(16) unsigned short As[128 * 32];
    __shared__ __align__(16) unsigned short Bs[128 * 32];
    const int tid  = threadIdx.x;
    const int lane = tid & 63;
    const int w    = tid >> 6;       // wave 0..3
    const int wm   = w >> 1;         // wave row (0..1)
    const int wn   = w & 1;          // wave col (0..1)
    const int l16  = lane & 15;
    const int quad = lane >> 4;
    const int m0 = blockIdx.y * 128;
    const int n0 = blockIdx.x * 128;

    f32x4 acc[4][4] = {};

    // staging: 8 KB per tile = 8 chunks of 1 KB; wave w does chunks {w, w+4}
    const int off0 = w * 1024 + lane * 16;
    const int off1 = (w + 4) * 1024 + lane * 16;
    const int r0 = off0 >> 6, cb0 = off0 & 63;   // row / byte-in-row (64 B rows)
    const int r1 = off1 >> 6, cb1 = off1 & 63;
    char* lA0 = (char*)As + w * 1024;
    char* lA1 = (char*)As + (w + 4) * 1024;
    char* lB0 = (char*)Bs + w * 1024;
    char* lB1 = (char*)Bs + (w + 4) * 1024;
    const size_t Kb = (size_t)K * 2;

    for (int k0 = 0; k0 < K; k0 += 32) {
        const char* a0 = (const char*)A + (size_t)(m0 + r0) * Kb + (size_t)k0 * 2 + cb0;
        const char* a1 = (const char*)A + (size_t)(m0 + r1) * Kb + (size_t)k0 * 2 + cb1;
        const char* b0 = (const char*)Bm + (size_t)(n0 + r0) * Kb + (size_t)k0 * 2 + cb0;
        const char* b1 = (const char*)Bm + (size_t)(n0 + r1) * Kb + (size_t)k0 * 2 + cb1;
        async_copy16(lA0, a0);
        async_copy16(lA1, a1);
        async_copy16(lB0, b0);
        async_copy16(lB1, b1);
        __syncthreads();   // drains vmcnt before barrier -> staged data visible

        bf16x8 af[4], bf[4];
#pragma unroll
        for (int mt = 0; mt < 4; ++mt) {
            int r = wm * 64 + mt * 16 + l16;
            af[mt] = *(const bf16x8*)(&As[r * 32 + quad * 8]);
        }
#pragma unroll
        for (int nt = 0; nt < 4; ++nt) {
            int r = wn * 64 + nt * 16 + l16;
            bf[nt] = *(const bf16x8*)(&Bs[r * 32 + quad * 8]);
        }
#pragma unroll
        for (int mt = 0; mt < 4; ++mt)
#pragma unroll
            for (int nt = 0; nt < 4; ++nt)
                acc[mt][nt] = __builtin_amdgcn_mfma_f32_16x16x32_bf16(af[mt], bf[nt], acc[mt][nt], 0, 0, 0);
        __syncthreads();   // protect LDS from next iteration's staging
    }

    // epilogue: C/D layout col = lane&15, row = quad*4 + reg
#pragma unroll
    for (int mt = 0; mt < 4; ++mt) {
#pragma unroll
        for (int nt = 0; nt < 4; ++nt) {
            const int col = n0 + wn * 64 + nt * 16 + l16;
            const int row = m0 + wm * 64 + mt * 16 + quad * 4;
#pragma unroll
            for (int rg = 0; rg < 4; ++rg)
                store_out(&C[(size_t)(row + rg) * N + col], acc[mt][nt][rg]);
        }
    }
}

// ---------------------------------------------------------------- recurrent scan
// One wave per (batch, head). W columns in registers; h broadcast via LDS.
// Fuses: depthwise causal conv(K=4) + SiLU on xi, and y = h * silu(g) epilogue.
#define SCAN_STEP(T, XI, XF, XR, G)                                            \
    {                                                                          \
        const float xi_raw = __bfloat162float(XI);                             \
        const float xf_v   = __bfloat162float(XF);                             \
        const float xr_v   = __bfloat162float(XR);                             \
        const float g_v    = __bfloat162float(G);                              \
        {   /* prefetch t+2 (clamped; last loads are unused) */                \
            const int tn = ((T) + 2 < S_) ? (T) + 2 : S_ - 1;                  \
            const __hip_bfloat16* rr = p + (size_t)tn * PROJ_;                 \
            XI = rr[0]; XF = rr[512]; XR = rr[1024]; G = rr[1536];             \
        }                                                                      \
        float xc = cw3 * xi_raw + cw2 * xm1 + cw1 * xm2 + cw0 * xm3;           \
        xm3 = xm2; xm2 = xm1; xm1 = xi_raw;                                    \
        const float xi_v = xc * fast_sigmoid(xc);                              \
        float fa0 = xf_v, fa1 = 0.f, ra0 = xr_v, ra1 = 0.f;                    \
        {                                                                      \
            const float4* h4 = (const float4*)h_sh;                            \
            _Pragma("unroll")                                                  \
            for (int jj = 0; jj < 16; ++jj) {                                  \
                const float4 hv = h4[jj];                                      \
                fa0 = fmaf(hv.x, Wf[4 * jj + 0], fa0);                         \
                fa1 = fmaf(hv.y, Wf[4 * jj + 1], fa1);                         \
                fa0 = fmaf(hv.z, Wf[4 * jj + 2], fa0);                         \
                fa1 = fmaf(hv.w, Wf[4 * jj + 3], fa1);                         \
                ra0 = fmaf(hv.x, Wr[4 * jj + 0], ra0);                         \
                ra1 = fmaf(hv.y, Wr[4 * jj + 1], ra1);                         \
                ra0 = fmaf(hv.z, Wr[4 * jj + 2], ra0);                         \
                ra1 = fmaf(hv.w, Wr[4 * jj + 3], ra1);                         \
            }                                                                  \
        }                                                                      \
        const float f_v = fast_sigmoid(fa0 + fa1);                             \
        const float r_v = fast_sigmoid(ra0 + ra1);                             \
        hr_sh[k] = h_me * r_v;                                                 \
        __syncthreads();                                                       \
        float za0 = xi_v, za1 = 0.f;                                           \
        {                                                                      \
            const float4* h4 = (const float4*)hr_sh;                           \
            _Pragma("unroll")                                                  \
            for (int jj = 0; jj < 16; ++jj) {                                  \
                const float4 hv = h4[jj];                                      \
                za0 = fmaf(hv.x, Wz[4 * jj + 0], za0);                         \
                za1 = fmaf(hv.y, Wz[4 * jj + 1], za1);                         \
                za0 = fmaf(hv.z, Wz[4 * jj + 2], za0);                         \
                za1 = fmaf(hv.w, Wz[4 * jj + 3], za1);                         \
            }                                                                  \
        }                                                                      \
        const float z_v = fast_tanh(za0 + za1);                                \
        const float hn  = f_v * h_me + (1.0f - f_v) * z_v;                     \
        __syncthreads();                                                       \
        h_sh[k] = hn;                                                          \
        h_me    = hn;                                                          \
        yout[(size_t)(T) * STATE_] = hn * (g_v * fast_sigmoid(g_v));           \
    }

__global__ __launch_bounds__(64, 1) void scan_kernel(
    const __hip_bfloat16* __restrict__ proj,   // (ROWS_, 2048) bf16
    const float* __restrict__ conv_w,          // (512, 4)
    const float* __restrict__ sw,              // (24, 64, 64)
    float* __restrict__ y)                     // (ROWS_, 512): h * silu(g)
{
    const int bn = blockIdx.x;          // 0..31
    const int b  = bn >> 3;
    const int n  = bn & 7;
    const int k  = threadIdx.x;         // 0..63 output index
    const int c  = n * HD_ + k;

    // W columns (thread k holds column k of each 64x64 matrix)
    float Wz[64], Wf[64], Wr[64];
    {
        const float* wz = sw + (size_t)n * 4096 + k;
        const float* wf = sw + (size_t)(n + 8) * 4096 + k;
        const float* wr = sw + (size_t)(n + 16) * 4096 + k;
#pragma unroll
        for (int j = 0; j < 64; ++j) {
            Wz[j] = wz[j * 64];
            Wf[j] = wf[j * 64];
            Wr[j] = wr[j * 64];
        }
    }
    const float cw0 = conv_w[c * 4 + 0];
    const float cw1 = conv_w[c * 4 + 1];
    const float cw2 = conv_w[c * 4 + 2];
    const float cw3 = conv_w[c * 4 + 3];

    __shared__ __align__(16) float h_sh[64];
    __shared__ __align__(16) float hr_sh[64];
    h_sh[k] = 0.0f;
    float h_me = 0.0f;
    float xm1 = 0.f, xm2 = 0.f, xm3 = 0.f;   // conv window x_{t-1}, x_{t-2}, x_{t-3}
    __syncthreads();

    const __hip_bfloat16* p = proj + (size_t)b * S_ * PROJ_ + c;
    float* yout = y + (size_t)b * S_ * STATE_ + c;

    // 2-deep prefetch: slot A = even t, slot B = odd t
    __hip_bfloat16 aXI, aXF, aXR, aG, bXI, bXF, bXR, bG;
    { const __hip_bfloat16* rr = p;          aXI = rr[0]; aXF = rr[512]; aXR = rr[1024]; aG = rr[1536]; }
    { const __hip_bfloat16* rr = p + PROJ_;  bXI = rr[0]; bXF = rr[512]; bXR = rr[1024]; bG = rr[1536]; }

    for (int t = 0; t < S_; t += 2) {
        SCAN_STEP(t,     aXI, aXF, aXR, aG);
        SCAN_STEP(t + 1, bXI, bXF, bXR, bG);
    }
}

// ---------------------------------------------------------------- RMSNorm + bf16 cast
__global__ __launch_bounds__(128) void rmsnorm_bf16(const float* __restrict__ y,
                                                    const float* __restrict__ nw,
                                                    unsigned short* __restrict__ out) {
    const int row = blockIdx.x;
    const int t   = threadIdx.x;                 // 0..127, 4 elems each
    const float4 v = ((const float4*)(y + (size_t)row * STATE_))[t];
    float ss = fmaf(v.x, v.x, fmaf(v.y, v.y, fmaf(v.z, v.z, v.w * v.w)));
#pragma unroll
    for (int off = 32; off > 0; off >>= 1) ss += __shfl_xor(ss, off, 64);
    __shared__ float wred[2];
    if ((t & 63) == 0) wred[t >> 6] = ss;
    __syncthreads();
    const float tot   = wred[0] + wred[1];
    const float scale = rsqrtf(tot * (1.0f / (float)STATE_) + 1e-6f);
    const float4 w4 = ((const float4*)nw)[t];
    ushort4 o;
    o.x = bfbits(v.x * scale * w4.x);
    o.y = bfbits(v.y * scale * w4.y);
    o.z = bfbits(v.z * scale * w4.z);
    o.w = bfbits(v.w * scale * w4.w);
    ((ushort4*)out)[(size_t)row * (STATE_ / 4) + t] = o;
}

// ---------------------------------------------------------------- launcher
extern "C" void kernel_launch(void* const* d_in, const int* in_sizes, int n_in,
                              void* d_out, int out_size, void* d_ws, size_t ws_size,
                              hipStream_t stream) {
    const float* x      = (const float*)d_in[0];   // (4,4096,1024)
    const float* w_in   = (const float*)d_in[1];   // (2048,1024)
    const float* conv_w = (const float*)d_in[2];   // (512,1,4)
    const float* sw     = (const float*)d_in[3];   // (24,64,64)
    const float* norm_w = (const float*)d_in[4];   // (512,)
    const float* w_out  = (const float*)d_in[5];   // (1024,512)
    float* out = (float*)d_out;                    // (4,4096,1024) fp32

    // workspace layout (bytes):
    //   [0,        33554432)  xbf   (ROWS_ x 1024 bf16)   -- later reused as y fp32 (same size)
    //   [33554432, 37748736)  w_inbf
    //   [37748736, 38797312)  w_outbf
    //   [38797312, 105906176) projbf (ROWS_ x 2048 bf16)  -- later reused as ybf
    char* ws = (char*)d_ws;
    unsigned short* xbf     = (unsigned short*)(ws + 0);
    unsigned short* w_inbf  = (unsigned short*)(ws + 33554432);
    unsigned short* w_outbf = (unsigned short*)(ws + 37748736);
    unsigned short* projbf  = (unsigned short*)(ws + 38797312);
    float*          yf      = (float*)(ws + 0);            // aliases xbf (dead after GEMM1)
    unsigned short* ybf     = (unsigned short*)(ws + 38797312); // aliases projbf (dead after scan)

    // 1) fp32 -> bf16 converts
    f2bf<<<(ROWS_ * D_ / 4 + 255) / 256, 256, 0, stream>>>(x, xbf, ROWS_ * D_ / 4);
    f2bf<<<(PROJ_ * D_ / 4 + 255) / 256, 256, 0, stream>>>(w_in, w_inbf, PROJ_ * D_ / 4);
    f2bf<<<(D_ * STATE_ / 4 + 255) / 256, 256, 0, stream>>>(w_out, w_outbf, D_ * STATE_ / 4);

    // 2) proj = x @ w_in^T   (16384 x 2048, K=1024) -> bf16
    gemm_bt<__hip_bfloat16><<<dim3(PROJ_ / 128, ROWS_ / 128), 256, 0, stream>>>(
        xbf, w_inbf, (__hip_bfloat16*)projbf, ROWS_, PROJ_, D_);

    // 3) recurrence (conv+silu+scan+silu(g) fused), writes y fp32
    scan_kernel<<<32, 64, 0, stream>>>((const __hip_bfloat16*)projbf, conv_w, sw, yf);

    // 4) RMSNorm + bf16 cast
    rmsnorm_bf16<<<ROWS_, 128, 0, stream>>>(yf, norm_w, ybf);

    // 5) out = y_norm @ w_out^T  (16384 x 1024, K=512) -> fp32
    gemm_bt<float><<<dim3(D_ / 128, ROWS_ / 128), 256, 0, stream>>>(
        ybf, w_outbf, out, ROWS_, D_, STATE_);
}

// Round 3
// 2423.430 us; speedup vs baseline: 1.2802x; 1.2802x over previous
//
#include <hip/hip_runtime.h>
#include <hip/hip_bf16.h>
#include <cstddef>

// ---------------------------------------------------------------- constants
#define B_      4
#define S_      4096
#define D_      1024
#define NH_     8
#define HD_     64
#define STATE_  512           // NH_*HD_
#define PROJ_   2048          // 4*STATE_
#define ROWS_   16384         // B_*S_

typedef float f32x4 __attribute__((ext_vector_type(4)));
typedef __bf16 bf16x8 __attribute__((ext_vector_type(8)));
typedef _Float16 f16x2 __attribute__((ext_vector_type(2)));

// ---------------------------------------------------------------- helpers
__device__ __forceinline__ unsigned short bfbits(float f) {
    __hip_bfloat16 h = __float2bfloat16(f);
    return __builtin_bit_cast(unsigned short, h);
}

__device__ __forceinline__ float b2f(unsigned short u) {
    union { unsigned int i; float f; } v;
    v.i = ((unsigned int)u) << 16;
    return v.f;
}

__device__ __forceinline__ float fast_sigmoid(float x) {
    return __builtin_amdgcn_rcpf(1.0f + __expf(-x));
}

__device__ __forceinline__ float fast_tanh(float x) {
    return 1.0f - 2.0f * __builtin_amdgcn_rcpf(__expf(2.0f * x) + 1.0f);
}

__device__ __forceinline__ void async_copy16(void* lds, const void* g) {
    __builtin_amdgcn_global_load_lds(
        (const __attribute__((address_space(1))) unsigned int*)g,
        (__attribute__((address_space(3))) unsigned int*)lds,
        16, 0, 0);
}

// pack two fp32 into f16x2 bits (v_cvt_pkrtz_f16_f32)
__device__ __forceinline__ unsigned int pkf16(float a, float b) {
    auto h = __builtin_amdgcn_cvt_pkrtz(a, b);   // __fp16 ext_vector(2)
    return __builtin_bit_cast(unsigned int, h);
}

__device__ __forceinline__ f16x2 u2h(unsigned int u) {
    return __builtin_bit_cast(f16x2, u);
}

// broadcast-read a f16-pair from lane `lane` (compile-time const)
__device__ __forceinline__ f16x2 rl_h2(unsigned int v, int lane) {
    int r = __builtin_amdgcn_readlane((int)v, lane);
    return __builtin_bit_cast(f16x2, r);
}

__device__ __forceinline__ float fdot2f(f16x2 a, f16x2 b, float c) {
    return __builtin_amdgcn_fdot2(a, b, c, false);
}

// pack (h[2p], h[2p+1]) as f16x2: lane k pairs with lane k^1 via DPP quad_perm
__device__ __forceinline__ unsigned int pack_pair(float v, bool oddlane) {
    int vb = __builtin_bit_cast(int, v);
    int pb = __builtin_amdgcn_mov_dpp(vb, 0xB1, 0xF, 0xF, true);  // lane ^ 1
    float p = __builtin_bit_cast(float, pb);
    float lo = oddlane ? p : v;
    float hi = oddlane ? v : p;
    return pkf16(lo, hi);
}

// ---------------------------------------------------------------- fp32 -> bf16 convert
__global__ __launch_bounds__(256) void f2bf(const float* __restrict__ in,
                                            unsigned short* __restrict__ out, int n4) {
    int i = blockIdx.x * 256 + threadIdx.x;
    if (i < n4) {
        float4 v = ((const float4*)in)[i];
        ushort4 o;
        o.x = bfbits(v.x); o.y = bfbits(v.y); o.z = bfbits(v.z); o.w = bfbits(v.w);
        ((ushort4*)out)[i] = o;
    }
}

// ---------------------------------------------------------------- GEMM  C[M,N] = A[M,K] * B[N,K]^T
__device__ __forceinline__ void store_out(float* p, float v) { *p = v; }
__device__ __forceinline__ void store_out(__hip_bfloat16* p, float v) { *p = __float2bfloat16(v); }

template <typename OutT>
__global__ __launch_bounds__(256, 1) void gemm_bt(const unsigned short* __restrict__ A,
                                                  const unsigned short* __restrict__ Bm,
                                                  OutT* __restrict__ C,
                                                  int M, int N, int K) {
    __shared__ __align__(16) unsigned short As[128 * 32];
    __shared__ __align__(16) unsigned short Bs[128 * 32];
    const int tid  = threadIdx.x;
    const int lane = tid & 63;
    const int w    = tid >> 6;
    const int wm   = w >> 1;
    const int wn   = w & 1;
    const int l16  = lane & 15;
    const int quad = lane >> 4;
    const int m0 = blockIdx.y * 128;
    const int n0 = blockIdx.x * 128;

    f32x4 acc[4][4] = {};

    const int off0 = w * 1024 + lane * 16;
    const int off1 = (w + 4) * 1024 + lane * 16;
    const int r0 = off0 >> 6, cb0 = off0 & 63;
    const int r1 = off1 >> 6, cb1 = off1 & 63;
    char* lA0 = (char*)As + w * 1024;
    char* lA1 = (char*)As + (w + 4) * 1024;
    char* lB0 = (char*)Bs + w * 1024;
    char* lB1 = (char*)Bs + (w + 4) * 1024;
    const size_t Kb = (size_t)K * 2;

    for (int k0 = 0; k0 < K; k0 += 32) {
        const char* a0 = (const char*)A + (size_t)(m0 + r0) * Kb + (size_t)k0 * 2 + cb0;
        const char* a1 = (const char*)A + (size_t)(m0 + r1) * Kb + (size_t)k0 * 2 + cb1;
        const char* b0 = (const char*)Bm + (size_t)(n0 + r0) * Kb + (size_t)k0 * 2 + cb0;
        const char* b1 = (const char*)Bm + (size_t)(n0 + r1) * Kb + (size_t)k0 * 2 + cb1;
        async_copy16(lA0, a0);
        async_copy16(lA1, a1);
        async_copy16(lB0, b0);
        async_copy16(lB1, b1);
        __syncthreads();

        bf16x8 af[4], bf[4];
#pragma unroll
        for (int mt = 0; mt < 4; ++mt) {
            int r = wm * 64 + mt * 16 + l16;
            af[mt] = *(const bf16x8*)(&As[r * 32 + quad * 8]);
        }
#pragma unroll
        for (int nt = 0; nt < 4; ++nt) {
            int r = wn * 64 + nt * 16 + l16;
            bf[nt] = *(const bf16x8*)(&Bs[r * 32 + quad * 8]);
        }
#pragma unroll
        for (int mt = 0; mt < 4; ++mt)
#pragma unroll
            for (int nt = 0; nt < 4; ++nt)
                acc[mt][nt] = __builtin_amdgcn_mfma_f32_16x16x32_bf16(af[mt], bf[nt], acc[mt][nt], 0, 0, 0);
        __syncthreads();
    }

#pragma unroll
    for (int mt = 0; mt < 4; ++mt) {
#pragma unroll
        for (int nt = 0; nt < 4; ++nt) {
            const int col = n0 + wn * 64 + nt * 16 + l16;
            const int row = m0 + wm * 64 + mt * 16 + quad * 4;
#pragma unroll
            for (int rg = 0; rg < 4; ++rg)
                store_out(&C[(size_t)(row + rg) * N + col], acc[mt][nt][rg]);
        }
    }
}

// ---------------------------------------------------------------- proj -> scan-friendly layout
// sc[((b*8+n)*S_ + t)*64 + k] = {xi, xf, xr, g} at channel c = n*64+k
__global__ __launch_bounds__(256) void transpose_scan(const unsigned short* __restrict__ proj,
                                                      ushort4* __restrict__ sc) {
    const int idx = blockIdx.x * 256 + threadIdx.x;   // 0 .. ROWS_*512-1
    const int c   = idx & 511;
    const int row = idx >> 9;
    const int b = row >> 12, t = row & 4095;
    const int n = c >> 6, kk = c & 63;
    const unsigned short* src = proj + (size_t)row * PROJ_ + c;
    ushort4 v;
    v.x = src[0];
    v.y = src[512];
    v.z = src[1024];
    v.w = src[1536];
    sc[((size_t)(b * 8 + n) * S_ + t) * 64 + kk] = v;
}

// ---------------------------------------------------------------- recurrent scan
// One wave per (batch, head). LDS-free: h broadcast via v_readlane of f16-pairs,
// matvecs via v_dot2_f32_f16 (W in packed f16, fp32 accum). One b64 gate load/step.
#define SCAN_STEP(T, V)                                                        \
    {                                                                          \
        const float xi_raw = b2f(V.x);                                         \
        const float xf_v   = b2f(V.y);                                         \
        const float xr_v   = b2f(V.z);                                         \
        const float g_v    = b2f(V.w);                                         \
        {   /* prefetch t+2 (clamped; tail loads unused) */                    \
            const int tn = ((T) + 2 < S_) ? (T) + 2 : S_ - 1;                  \
            V = pin[(size_t)tn * 64];                                          \
        }                                                                      \
        float xc = fmaf(cw3, xi_raw, fmaf(cw2, xm1, fmaf(cw1, xm2, cw0 * xm3)));\
        xm3 = xm2; xm2 = xm1; xm1 = xi_raw;                                    \
        const float xi_v = xc * fast_sigmoid(xc);                              \
        float fa0 = xf_v, fa1 = 0.f, fa2 = 0.f, fa3 = 0.f;                     \
        float ra0 = xr_v, ra1 = 0.f, ra2 = 0.f, ra3 = 0.f;                     \
        _Pragma("unroll")                                                      \
        for (int jp = 0; jp < 32; jp += 4) {                                   \
            const f16x2 h0 = rl_h2(hpk, 2 * jp);                               \
            const f16x2 h1 = rl_h2(hpk, 2 * jp + 2);                           \
            const f16x2 h2 = rl_h2(hpk, 2 * jp + 4);                           \
            const f16x2 h3 = rl_h2(hpk, 2 * jp + 6);                           \
            fa0 = fdot2f(h0, u2h(Wf2[jp]),     fa0);                           \
            ra0 = fdot2f(h0, u2h(Wr2[jp]),     ra0);                           \
            fa1 = fdot2f(h1, u2h(Wf2[jp + 1]), fa1);                           \
            ra1 = fdot2f(h1, u2h(Wr2[jp + 1]), ra1);                           \
            fa2 = fdot2f(h2, u2h(Wf2[jp + 2]), fa2);                           \
            ra2 = fdot2f(h2, u2h(Wr2[jp + 2]), ra2);                           \
            fa3 = fdot2f(h3, u2h(Wf2[jp + 3]), fa3);                           \
            ra3 = fdot2f(h3, u2h(Wr2[jp + 3]), ra3);                           \
        }                                                                      \
        const float f_v = fast_sigmoid((fa0 + fa1) + (fa2 + fa3));             \
        const float r_v = fast_sigmoid((ra0 + ra1) + (ra2 + ra3));             \
        const unsigned int hrpk = pack_pair(h_me * r_v, oddlane);              \
        float za0 = xi_v, za1 = 0.f, za2 = 0.f, za3 = 0.f;                     \
        _Pragma("unroll")                                                      \
        for (int jp = 0; jp < 32; jp += 4) {                                   \
            za0 = fdot2f(rl_h2(hrpk, 2 * jp),     u2h(Wz2[jp]),     za0);      \
            za1 = fdot2f(rl_h2(hrpk, 2 * jp + 2), u2h(Wz2[jp + 1]), za1);      \
            za2 = fdot2f(rl_h2(hrpk, 2 * jp + 4), u2h(Wz2[jp + 2]), za2);      \
            za3 = fdot2f(rl_h2(hrpk, 2 * jp + 6), u2h(Wz2[jp + 3]), za3);      \
        }                                                                      \
        const float z_v = fast_tanh((za0 + za1) + (za2 + za3));                \
        const float hn  = fmaf(f_v, h_me - z_v, z_v);                          \
        h_me = hn;                                                             \
        hpk  = pack_pair(hn, oddlane);                                         \
        yout[(size_t)(T) * STATE_] = hn * (g_v * fast_sigmoid(g_v));           \
    }

__global__ __launch_bounds__(64, 1) void scan_kernel(
    const ushort4* __restrict__ scanin,        // ((b*8+n)*S + t)*64 + k -> {xi,xf,xr,g}
    const float* __restrict__ conv_w,          // (512, 4)
    const float* __restrict__ sw,              // (24, 64, 64)
    float* __restrict__ y)                     // (ROWS_, 512): h * silu(g)
{
    const int bn = blockIdx.x;          // 0..31
    const int b  = bn >> 3;
    const int n  = bn & 7;
    const int k  = threadIdx.x;         // 0..63 output column
    const int c  = n * HD_ + k;
    const bool oddlane = (k & 1) != 0;

    // W columns packed as f16 j-pairs: thread k holds column k
    unsigned int Wz2[32], Wf2[32], Wr2[32];
    {
        const float* wz = sw + (size_t)n * 4096 + k;
        const float* wf = wz + 8 * 4096;
        const float* wr = wz + 16 * 4096;
#pragma unroll
        for (int jp = 0; jp < 32; ++jp) {
            Wz2[jp] = pkf16(wz[(2 * jp) * 64], wz[(2 * jp + 1) * 64]);
            Wf2[jp] = pkf16(wf[(2 * jp) * 64], wf[(2 * jp + 1) * 64]);
            Wr2[jp] = pkf16(wr[(2 * jp) * 64], wr[(2 * jp + 1) * 64]);
        }
    }
    const float cw0 = conv_w[c * 4 + 0];
    const float cw1 = conv_w[c * 4 + 1];
    const float cw2 = conv_w[c * 4 + 2];
    const float cw3 = conv_w[c * 4 + 3];

    float h_me = 0.0f;
    unsigned int hpk = 0;               // f16x2(0,0)
    float xm1 = 0.f, xm2 = 0.f, xm3 = 0.f;

    const ushort4* pin = scanin + (size_t)bn * S_ * 64 + k;
    float* yout = y + (size_t)b * S_ * STATE_ + c;

    ushort4 aV = pin[0];
    ushort4 bV = pin[64];

    for (int t = 0; t < S_; t += 2) {
        SCAN_STEP(t,     aV);
        SCAN_STEP(t + 1, bV);
    }
}

// ---------------------------------------------------------------- RMSNorm + bf16 cast
__global__ __launch_bounds__(128) void rmsnorm_bf16(const float* __restrict__ y,
                                                    const float* __restrict__ nw,
                                                    unsigned short* __restrict__ out) {
    const int row = blockIdx.x;
    const int t   = threadIdx.x;
    const float4 v = ((const float4*)(y + (size_t)row * STATE_))[t];
    float ss = fmaf(v.x, v.x, fmaf(v.y, v.y, fmaf(v.z, v.z, v.w * v.w)));
#pragma unroll
    for (int off = 32; off > 0; off >>= 1) ss += __shfl_xor(ss, off, 64);
    __shared__ float wred[2];
    if ((t & 63) == 0) wred[t >> 6] = ss;
    __syncthreads();
    const float tot   = wred[0] + wred[1];
    const float scale = rsqrtf(tot * (1.0f / (float)STATE_) + 1e-6f);
    const float4 w4 = ((const float4*)nw)[t];
    ushort4 o;
    o.x = bfbits(v.x * scale * w4.x);
    o.y = bfbits(v.y * scale * w4.y);
    o.z = bfbits(v.z * scale * w4.z);
    o.w = bfbits(v.w * scale * w4.w);
    ((ushort4*)out)[(size_t)row * (STATE_ / 4) + t] = o;
}

// ---------------------------------------------------------------- launcher
extern "C" void kernel_launch(void* const* d_in, const int* in_sizes, int n_in,
                              void* d_out, int out_size, void* d_ws, size_t ws_size,
                              hipStream_t stream) {
    const float* x      = (const float*)d_in[0];
    const float* w_in   = (const float*)d_in[1];
    const float* conv_w = (const float*)d_in[2];
    const float* sw     = (const float*)d_in[3];
    const float* norm_w = (const float*)d_in[4];
    const float* w_out  = (const float*)d_in[5];
    float* out = (float*)d_out;                    // (4,4096,1024) fp32 = 64 MiB

    // workspace layout (bytes):
    //   [0,        33554432)  xbf (bf16)      -- reused as y fp32 after GEMM1
    //   [33554432, 37748736)  w_inbf
    //   [37748736, 38797312)  w_outbf
    //   [38797312, 105906176) scanin (ushort4) -- reused as ybf after scan
    // projbf (16384x2048 bf16 = 64 MiB) lives in d_out until transpose_scan reads it.
    char* ws = (char*)d_ws;
    unsigned short* xbf     = (unsigned short*)(ws + 0);
    unsigned short* w_inbf  = (unsigned short*)(ws + 33554432);
    unsigned short* w_outbf = (unsigned short*)(ws + 37748736);
    ushort4*        scanin  = (ushort4*)(ws + 38797312);
    float*          yf      = (float*)(ws + 0);
    unsigned short* ybf     = (unsigned short*)(ws + 38797312);
    unsigned short* projbf  = (unsigned short*)d_out;   // scratch inside d_out

    // 1) fp32 -> bf16 converts
    f2bf<<<(ROWS_ * D_ / 4 + 255) / 256, 256, 0, stream>>>(x, xbf, ROWS_ * D_ / 4);
    f2bf<<<(PROJ_ * D_ / 4 + 255) / 256, 256, 0, stream>>>(w_in, w_inbf, PROJ_ * D_ / 4);
    f2bf<<<(D_ * STATE_ / 4 + 255) / 256, 256, 0, stream>>>(w_out, w_outbf, D_ * STATE_ / 4);

    // 2) proj = x @ w_in^T -> bf16 (into d_out scratch)
    gemm_bt<__hip_bfloat16><<<dim3(PROJ_ / 128, ROWS_ / 128), 256, 0, stream>>>(
        xbf, w_inbf, (__hip_bfloat16*)projbf, ROWS_, PROJ_, D_);

    // 3) rearrange proj for the scan (1 coalesced b64 load per step per lane)
    transpose_scan<<<ROWS_ * 512 / 256, 256, 0, stream>>>(projbf, scanin);

    // 4) recurrence (conv+silu+scan+silu(g) fused), writes y fp32
    scan_kernel<<<32, 64, 0, stream>>>(scanin, conv_w, sw, yf);

    // 5) RMSNorm + bf16 cast
    rmsnorm_bf16<<<ROWS_, 128, 0, stream>>>(yf, norm_w, ybf);

    // 6) out = y_norm @ w_out^T (overwrites the projbf scratch)
    gemm_bt<float><<<dim3(D_ / 128, ROWS_ / 128), 256, 0, stream>>>(
        ybf, w_outbf, out, ROWS_, D_, STATE_);
}